// Round 1
// baseline (20527.036 us; speedup 1.0000x reference)
//
#include <hip/hip_runtime.h>
#include <cstddef>
#include <cstdint>

// Problem sizes (fixed by the reference).
constexpr int N_ = 8192;   // rows of x / sims
constexpr int D_ = 2048;   // onehot feature dim
constexpr int M_ = 4096;   // item dim

// ---------------------------------------------------------------------------
// helpers
// ---------------------------------------------------------------------------
__device__ __forceinline__ void wave_reduce_add2(float& a, float& b) {
#pragma unroll
  for (int o = 1; o < 64; o <<= 1) {
    a += __shfl_xor(a, o, 64);
    b += __shfl_xor(b, o, 64);
  }
}

// ---------------------------------------------------------------------------
// means_rows[i] = sum_j x[i,j] / (count_j(x[i,j]>0) + 1e-5)
// one block per row
// ---------------------------------------------------------------------------
__global__ __launch_bounds__(256) void krowstats(const float* __restrict__ x,
                                                 float* __restrict__ mr) {
  __shared__ float sb[8];
  const int i = blockIdx.x;
  const float4* xr = reinterpret_cast<const float4*>(x + (size_t)i * M_);
  float s = 0.f, c = 0.f;
  for (int t = threadIdx.x; t < M_ / 4; t += 256) {
    float4 v = xr[t];
    s += v.x + v.y + v.z + v.w;
    c += (v.x > 0.f ? 1.f : 0.f) + (v.y > 0.f ? 1.f : 0.f) +
         (v.z > 0.f ? 1.f : 0.f) + (v.w > 0.f ? 1.f : 0.f);
  }
  wave_reduce_add2(s, c);
  const int lane = threadIdx.x & 63, w = threadIdx.x >> 6;
  if (lane == 0) { sb[w] = s; sb[4 + w] = c; }
  __syncthreads();
  if (threadIdx.x == 0) {
    s = sb[0] + sb[1] + sb[2] + sb[3];
    c = sb[4] + sb[5] + sb[6] + sb[7];
    mr[i] = s / (c + 1e-5f);
  }
}

// ---------------------------------------------------------------------------
// column partial sums: 64 row-slices, deterministic (no atomics)
// grid (M/256, 64); thread owns one column within its slice
// ---------------------------------------------------------------------------
__global__ __launch_bounds__(256) void kcolpart(const float* __restrict__ x,
                                                float* __restrict__ ps,
                                                float* __restrict__ pc) {
  const int j = blockIdx.x * 256 + threadIdx.x;
  const int slice = blockIdx.y;
  const int i0 = slice * (N_ / 64);
  float s = 0.f, c = 0.f;
  for (int i = i0; i < i0 + N_ / 64; ++i) {
    float v = x[(size_t)i * M_ + j];
    s += v;
    c += (v > 0.f ? 1.f : 0.f);
  }
  ps[(size_t)slice * M_ + j] = s;
  pc[(size_t)slice * M_ + j] = c;
}

__global__ __launch_bounds__(256) void kcolred(const float* __restrict__ ps,
                                               const float* __restrict__ pc,
                                               float* __restrict__ mc) {
  const int j = blockIdx.x * 256 + threadIdx.x;
  float s = 0.f, c = 0.f;
  for (int sl = 0; sl < 64; ++sl) {
    s += ps[(size_t)sl * M_ + j];
    c += pc[(size_t)sl * M_ + j];
  }
  mc[j] = s / (c + 1e-5f);
}

// scal[0] = mean(mr), scal[1] = mean(mc)   (grid = 2 blocks)
__global__ __launch_bounds__(256) void kmeans(const float* __restrict__ mr,
                                              const float* __restrict__ mc,
                                              float* __restrict__ scal) {
  __shared__ float sb[4];
  const float* src = blockIdx.x ? mc : mr;
  const int n = blockIdx.x ? M_ : N_;
  float s = 0.f, d = 0.f;
  for (int t = threadIdx.x; t < n; t += 256) s += src[t];
  wave_reduce_add2(s, d);
  const int lane = threadIdx.x & 63, w = threadIdx.x >> 6;
  if (lane == 0) sb[w] = s;
  __syncthreads();
  if (threadIdx.x == 0)
    scal[blockIdx.x] = (sb[0] + sb[1] + sb[2] + sb[3]) / (float)n;
}

// ---------------------------------------------------------------------------
// sims = tr_onehot @ tr_onehot_bool^T, diagonal zeroed on write.
// 128x128 tile, 256 threads, 8x8 micro-tile, BK=16, fp32 vector FMA.
// ---------------------------------------------------------------------------
__global__ __launch_bounds__(256) void kgemm1(const float* __restrict__ A,
                                              const float* __restrict__ B,
                                              float* __restrict__ C) {
  constexpr int BM = 128, BK = 16, LDT = BM + 4;  // 132, keeps f4 alignment
  __shared__ float As[BK][LDT];
  __shared__ float Bs[BK][LDT];
  const int bi = blockIdx.y, bj = blockIdx.x;
  const int tid = threadIdx.x;
  const int tx = tid & 15, ty = tid >> 4;
  const int row0 = bi * BM, col0 = bj * BM;
  float acc[8][8] = {};

  for (int k0 = 0; k0 < D_; k0 += BK) {
#pragma unroll
    for (int p = 0; p < 2; ++p) {
      const int idx = tid + p * 256;         // 512 float4s per operand tile
      const int r = idx >> 2, c4 = idx & 3;  // row in tile, float4 col
      float4 va = *reinterpret_cast<const float4*>(
          A + (size_t)(row0 + r) * D_ + k0 + c4 * 4);
      As[c4 * 4 + 0][r] = va.x; As[c4 * 4 + 1][r] = va.y;
      As[c4 * 4 + 2][r] = va.z; As[c4 * 4 + 3][r] = va.w;
      float4 vb = *reinterpret_cast<const float4*>(
          B + (size_t)(col0 + r) * D_ + k0 + c4 * 4);
      Bs[c4 * 4 + 0][r] = vb.x; Bs[c4 * 4 + 1][r] = vb.y;
      Bs[c4 * 4 + 2][r] = vb.z; Bs[c4 * 4 + 3][r] = vb.w;
    }
    __syncthreads();
#pragma unroll
    for (int kk = 0; kk < BK; ++kk) {
      float a[8], b[8];
      *reinterpret_cast<float4*>(&a[0]) =
          *reinterpret_cast<const float4*>(&As[kk][ty * 8]);
      *reinterpret_cast<float4*>(&a[4]) =
          *reinterpret_cast<const float4*>(&As[kk][ty * 8 + 4]);
      *reinterpret_cast<float4*>(&b[0]) =
          *reinterpret_cast<const float4*>(&Bs[kk][tx * 8]);
      *reinterpret_cast<float4*>(&b[4]) =
          *reinterpret_cast<const float4*>(&Bs[kk][tx * 8 + 4]);
#pragma unroll
      for (int u = 0; u < 8; ++u)
#pragma unroll
        for (int v = 0; v < 8; ++v) acc[u][v] = fmaf(a[u], b[v], acc[u][v]);
    }
    __syncthreads();
  }

  if (bi != bj) {
#pragma unroll
    for (int u = 0; u < 8; ++u) {
      const size_t base = (size_t)(row0 + ty * 8 + u) * N_ + col0 + tx * 8;
      *reinterpret_cast<float4*>(C + base) =
          make_float4(acc[u][0], acc[u][1], acc[u][2], acc[u][3]);
      *reinterpret_cast<float4*>(C + base + 4) =
          make_float4(acc[u][4], acc[u][5], acc[u][6], acc[u][7]);
    }
  } else {  // tile contains the diagonal -> scalar stores with diag zero
#pragma unroll
    for (int u = 0; u < 8; ++u) {
      const int gi = row0 + ty * 8 + u;
#pragma unroll
      for (int v = 0; v < 8; ++v) {
        const int gj = col0 + tx * 8 + v;
        C[(size_t)gi * N_ + gj] = (gi == gj) ? 0.f : acc[u][v];
      }
    }
  }
}

// ---------------------------------------------------------------------------
// per-row max of sims (after diag zero)
// ---------------------------------------------------------------------------
__global__ __launch_bounds__(256) void krowmax(const float* __restrict__ sims,
                                               float* __restrict__ rmax) {
  __shared__ float sb[4];
  const int i = blockIdx.x;
  const float4* r = reinterpret_cast<const float4*>(sims + (size_t)i * N_);
  float m = -1e30f;
  for (int t = threadIdx.x; t < N_ / 4; t += 256) {
    float4 v = r[t];
    m = fmaxf(m, fmaxf(fmaxf(v.x, v.y), fmaxf(v.z, v.w)));
  }
#pragma unroll
  for (int o = 1; o < 64; o <<= 1) m = fmaxf(m, __shfl_xor(m, o, 64));
  const int lane = threadIdx.x & 63, w = threadIdx.x >> 6;
  if (lane == 0) sb[w] = m;
  __syncthreads();
  if (threadIdx.x == 0)
    rmax[i] = fmaxf(fmaxf(sb[0], sb[1]), fmaxf(sb[2], sb[3]));
}

// rtemp[j] = 1 / (pow(rmax[j]+1e-3, gamma) * beta)
__global__ __launch_bounds__(256) void ktemp(const float* __restrict__ rmax,
                                             const float* __restrict__ gamma,
                                             const float* __restrict__ beta,
                                             float* __restrict__ rtemp) {
  const int j = blockIdx.x * 256 + threadIdx.x;
  if (j < N_) {
    float t = powf(rmax[j] + 0.001f, gamma[0]) * beta[0];
    rtemp[j] = 1.0f / t;
  }
}

// ---------------------------------------------------------------------------
// row softmax of sims[i,j] * rtemp[j], in place. one block per row.
// ---------------------------------------------------------------------------
__global__ __launch_bounds__(256) void ksoftmax(float* __restrict__ sims,
                                                const float* __restrict__ rtemp) {
  __shared__ float srow[N_];  // 32 KB
  __shared__ float sb[8];
  const int i = blockIdx.x;
  float* row = sims + (size_t)i * N_;
  const int lane = threadIdx.x & 63, w = threadIdx.x >> 6;

  float m = -1e30f;
  for (int t = threadIdx.x; t < N_ / 4; t += 256) {
    float4 v = reinterpret_cast<const float4*>(row)[t];
    float4 rt = reinterpret_cast<const float4*>(rtemp)[t];
    v.x *= rt.x; v.y *= rt.y; v.z *= rt.z; v.w *= rt.w;
    reinterpret_cast<float4*>(srow)[t] = v;
    m = fmaxf(m, fmaxf(fmaxf(v.x, v.y), fmaxf(v.z, v.w)));
  }
#pragma unroll
  for (int o = 1; o < 64; o <<= 1) m = fmaxf(m, __shfl_xor(m, o, 64));
  if (lane == 0) sb[w] = m;
  __syncthreads();
  m = fmaxf(fmaxf(sb[0], sb[1]), fmaxf(sb[2], sb[3]));

  float s = 0.f;
  for (int t = threadIdx.x; t < N_ / 4; t += 256) {
    float4 v = reinterpret_cast<float4*>(srow)[t];
    v.x = __expf(v.x - m); v.y = __expf(v.y - m);
    v.z = __expf(v.z - m); v.w = __expf(v.w - m);
    reinterpret_cast<float4*>(srow)[t] = v;
    s += v.x + v.y + v.z + v.w;
  }
#pragma unroll
  for (int o = 1; o < 64; o <<= 1) s += __shfl_xor(s, o, 64);
  if (lane == 0) sb[4 + w] = s;
  __syncthreads();
  s = sb[4] + sb[5] + sb[6] + sb[7];
  const float inv = 1.0f / s;
  for (int t = threadIdx.x; t < N_ / 4; t += 256) {
    float4 v = reinterpret_cast<float4*>(srow)[t];
    v.x *= inv; v.y *= inv; v.z *= inv; v.w *= inv;
    reinterpret_cast<float4*>(row)[t] = v;
  }
}

// ---------------------------------------------------------------------------
// fused triple GEMM + epilogue:
//   s1 = sim@x, s2 = sim@mask, s3 = sim@(mask*mr)
//   out = s1/(s2+1e-4) + c0*(mr_i - s3/(s2+1e-4)) + c1*(mc_j - mcm) + c2*(mr_i - mrm)
// 128x64 tile, 256 threads, 8x4 micro-tile, 3 accumulators.
// ---------------------------------------------------------------------------
__global__ __launch_bounds__(256) void kfused(const float* __restrict__ sim,
                                              const float* __restrict__ x,
                                              const float* __restrict__ mr,
                                              const float* __restrict__ mc,
                                              const float* __restrict__ scal,
                                              const float* __restrict__ coef,
                                              float* __restrict__ out) {
  constexpr int BM = 128, BN = 64, BK = 16;
  __shared__ float As[BK][BM + 4];   // 16 x 132
  __shared__ float Bx[BK][BN + 4];   // 16 x 68
  __shared__ float Bm[BK][BN + 4];
  __shared__ float Bq[BK][BN + 4];   // mask * means_rows[k]
  const int bi = blockIdx.y, bj = blockIdx.x;
  const int tid = threadIdx.x;
  const int tx = tid & 15, ty = tid >> 4;
  const int row0 = bi * BM, col0 = bj * BN;
  float acc1[8][4] = {}, acc2[8][4] = {}, acc3[8][4] = {};

  for (int k0 = 0; k0 < N_; k0 += BK) {
    // A (sim) tile: 128x16, transposed store
#pragma unroll
    for (int p = 0; p < 2; ++p) {
      const int idx = tid + p * 256;
      const int r = idx >> 2, c4 = idx & 3;
      float4 va = *reinterpret_cast<const float4*>(
          sim + (size_t)(row0 + r) * N_ + k0 + c4 * 4);
      As[c4 * 4 + 0][r] = va.x; As[c4 * 4 + 1][r] = va.y;
      As[c4 * 4 + 2][r] = va.z; As[c4 * 4 + 3][r] = va.w;
    }
    // B tiles from x: 16x64, one float4 per thread
    {
      const int k = tid >> 4, c4 = tid & 15;
      float4 v = *reinterpret_cast<const float4*>(
          x + (size_t)(k0 + k) * M_ + col0 + c4 * 4);
      const float mrk = mr[k0 + k];
      const float m0 = v.x > 0.f ? 1.f : 0.f, m1 = v.y > 0.f ? 1.f : 0.f;
      const float m2 = v.z > 0.f ? 1.f : 0.f, m3 = v.w > 0.f ? 1.f : 0.f;
      Bx[k][c4 * 4 + 0] = v.x; Bx[k][c4 * 4 + 1] = v.y;
      Bx[k][c4 * 4 + 2] = v.z; Bx[k][c4 * 4 + 3] = v.w;
      Bm[k][c4 * 4 + 0] = m0;  Bm[k][c4 * 4 + 1] = m1;
      Bm[k][c4 * 4 + 2] = m2;  Bm[k][c4 * 4 + 3] = m3;
      Bq[k][c4 * 4 + 0] = m0 * mrk; Bq[k][c4 * 4 + 1] = m1 * mrk;
      Bq[k][c4 * 4 + 2] = m2 * mrk; Bq[k][c4 * 4 + 3] = m3 * mrk;
    }
    __syncthreads();
#pragma unroll
    for (int kk = 0; kk < BK; ++kk) {
      float a[8];
      *reinterpret_cast<float4*>(&a[0]) =
          *reinterpret_cast<const float4*>(&As[kk][ty * 8]);
      *reinterpret_cast<float4*>(&a[4]) =
          *reinterpret_cast<const float4*>(&As[kk][ty * 8 + 4]);
      const float4 bx = *reinterpret_cast<const float4*>(&Bx[kk][tx * 4]);
      const float4 bm = *reinterpret_cast<const float4*>(&Bm[kk][tx * 4]);
      const float4 bq = *reinterpret_cast<const float4*>(&Bq[kk][tx * 4]);
#pragma unroll
      for (int u = 0; u < 8; ++u) {
        acc1[u][0] = fmaf(a[u], bx.x, acc1[u][0]);
        acc1[u][1] = fmaf(a[u], bx.y, acc1[u][1]);
        acc1[u][2] = fmaf(a[u], bx.z, acc1[u][2]);
        acc1[u][3] = fmaf(a[u], bx.w, acc1[u][3]);
        acc2[u][0] = fmaf(a[u], bm.x, acc2[u][0]);
        acc2[u][1] = fmaf(a[u], bm.y, acc2[u][1]);
        acc2[u][2] = fmaf(a[u], bm.z, acc2[u][2]);
        acc2[u][3] = fmaf(a[u], bm.w, acc2[u][3]);
        acc3[u][0] = fmaf(a[u], bq.x, acc3[u][0]);
        acc3[u][1] = fmaf(a[u], bq.y, acc3[u][1]);
        acc3[u][2] = fmaf(a[u], bq.z, acc3[u][2]);
        acc3[u][3] = fmaf(a[u], bq.w, acc3[u][3]);
      }
    }
    __syncthreads();
  }

  const float c0 = coef[0], c1 = coef[1], c2 = coef[2];
  const float mrm = scal[0], mcm = scal[1];
  const int gj = col0 + tx * 4;
  const float4 mcv = *reinterpret_cast<const float4*>(mc + gj);
  const float mcc[4] = {mcv.x - mcm, mcv.y - mcm, mcv.z - mcm, mcv.w - mcm};
#pragma unroll
  for (int u = 0; u < 8; ++u) {
    const int gi = row0 + ty * 8 + u;
    const float mri = mr[gi];
    const float radd = c2 * (mri - mrm);
    float o[4];
#pragma unroll
    for (int v = 0; v < 4; ++v) {
      const float sc = acc2[u][v] + 1e-4f;
      const float inv = 1.0f / sc;
      o[v] = acc1[u][v] * inv + c0 * (mri - acc3[u][v] * inv) + c1 * mcc[v] + radd;
    }
    *reinterpret_cast<float4*>(out + (size_t)gi * M_ + gj) =
        make_float4(o[0], o[1], o[2], o[3]);
  }
}

// ---------------------------------------------------------------------------
// launch
// ---------------------------------------------------------------------------
extern "C" void kernel_launch(void* const* d_in, const int* in_sizes, int n_in,
                              void* d_out, int out_size, void* d_ws,
                              size_t ws_size, hipStream_t stream) {
  const float* t1 = (const float*)d_in[0];     // tr_onehot      [N,D]
  const float* t2 = (const float*)d_in[1];     // tr_onehot_bool [N,D]
  const float* x = (const float*)d_in[2];      // x              [N,M]
  const float* beta = (const float*)d_in[3];   // [1]
  const float* gamma = (const float*)d_in[4];  // [1]
  const float* coef = (const float*)d_in[5];   // [3]
  float* out = (float*)d_out;

  // workspace layout (floats):
  //   sims  [N*N]                         268.4 MB
  //   aux: mr[N] | mc[M] | rmax[N] | rtemp[N] | scal[2] | colpart[2*64*M]
  float* ws = (float*)d_ws;
  float* sims = ws;
  float* aux = ws + (size_t)N_ * N_;
  float* mr = aux;                // N
  float* mc = aux + 8192;         // M
  float* rmax = aux + 12288;      // N
  float* rtemp = aux + 20480;     // N
  float* scal = aux + 28672;      // 2
  float* cps = aux + 28680;       // 64*M
  float* cpc = cps + (size_t)64 * M_;

  krowstats<<<N_, 256, 0, stream>>>(x, mr);
  kcolpart<<<dim3(M_ / 256, 64), 256, 0, stream>>>(x, cps, cpc);
  kcolred<<<M_ / 256, 256, 0, stream>>>(cps, cpc, mc);
  kmeans<<<2, 256, 0, stream>>>(mr, mc, scal);

  kgemm1<<<dim3(N_ / 128, N_ / 128), 256, 0, stream>>>(t1, t2, sims);
  krowmax<<<N_, 256, 0, stream>>>(sims, rmax);
  ktemp<<<N_ / 256, 256, 0, stream>>>(rmax, gamma, beta, rtemp);
  ksoftmax<<<N_, 256, 0, stream>>>(sims, rtemp);

  kfused<<<dim3(M_ / 64, N_ / 128), 256, 0, stream>>>(sims, x, mr, mc, scal,
                                                      coef, out);
}

// Round 3
// 4306.439 us; speedup vs baseline: 4.7666x; 4.7666x over previous
//
#include <hip/hip_runtime.h>
#include <cstddef>
#include <cstdint>

constexpr int N_ = 8192;   // rows of x / sims
constexpr int D_ = 2048;   // onehot feature dim
constexpr int M_ = 4096;   // item dim

typedef unsigned short u16;
typedef __attribute__((ext_vector_type(8))) unsigned short us8;
typedef __attribute__((ext_vector_type(8))) short bf8;     // 8 x bf16 (4 VGPR)
typedef __attribute__((ext_vector_type(4))) float f4;

// ---------------------------------------------------------------------------
// helpers
// ---------------------------------------------------------------------------
__device__ __forceinline__ u16 f2b(float f) {   // fp32 -> bf16 RNE
  union { float f; unsigned u; } v{f};
  unsigned r = v.u + 0x7fffu + ((v.u >> 16) & 1u);
  return (u16)(r >> 16);
}
__device__ __forceinline__ float b2f(u16 h) {
  union { unsigned u; float f; } v{(unsigned)h << 16};
  return v.f;
}
__device__ __forceinline__ void wave_reduce_add2(float& a, float& b) {
#pragma unroll
  for (int o = 1; o < 64; o <<= 1) {
    a += __shfl_xor(a, o, 64);
    b += __shfl_xor(b, o, 64);
  }
}
// async global->LDS, 16B per lane. lds base must be wave-uniform.
__device__ __forceinline__ void gload16(const void* g, void* lds) {
  __builtin_amdgcn_global_load_lds(
      (const __attribute__((address_space(1))) unsigned int*)g,
      (__attribute__((address_space(3))) unsigned int*)lds, 16, 0, 0);
}
__device__ __forceinline__ f4 mfma16(bf8 a, bf8 b, f4 c) {
  return __builtin_amdgcn_mfma_f32_16x16x32_bf16(a, b, c, 0, 0, 0);
}

// ---------------------------------------------------------------------------
// fp32 -> bf16 convert (grid-stride, 8 elems/thread/iter)
// ---------------------------------------------------------------------------
__global__ __launch_bounds__(256) void kcvt(const float* __restrict__ s,
                                            u16* __restrict__ d, int n8) {
  for (int i = blockIdx.x * 256 + threadIdx.x; i < n8; i += gridDim.x * 256) {
    float4 a = ((const float4*)s)[i * 2 + 0];
    float4 b = ((const float4*)s)[i * 2 + 1];
    us8 v;
    v[0] = f2b(a.x); v[1] = f2b(a.y); v[2] = f2b(a.z); v[3] = f2b(a.w);
    v[4] = f2b(b.x); v[5] = f2b(b.y); v[6] = f2b(b.z); v[7] = f2b(b.w);
    ((us8*)d)[i] = v;
  }
}

// transpose + convert: x[8192][4096] f32 -> xt[4096][8192] bf16
__global__ __launch_bounds__(256) void kcvtxt(const float* __restrict__ x,
                                              u16* __restrict__ xt) {
  __shared__ u16 sb[64][72];
  const int k0 = blockIdx.y * 64;  // x row block (k)
  const int n0 = blockIdx.x * 64;  // x col block (n)
  const int t = threadIdx.x;
#pragma unroll
  for (int p = 0; p < 4; ++p) {
    int r = (t >> 4) + 16 * p, c = (t & 15) * 4;
    float4 v = *(const float4*)&x[(size_t)(k0 + r) * M_ + n0 + c];
    sb[r][c] = f2b(v.x); sb[r][c + 1] = f2b(v.y);
    sb[r][c + 2] = f2b(v.z); sb[r][c + 3] = f2b(v.w);
  }
  __syncthreads();
#pragma unroll
  for (int q = 0; q < 2; ++q) {
    int o = (q * 256 + t) * 8;
    int nl = o >> 6, kc = o & 63;
    us8 v;
#pragma unroll
    for (int j = 0; j < 8; ++j) v[j] = sb[kc + j][nl];
    *(us8*)&xt[(size_t)(n0 + nl) * N_ + k0 + kc] = v;
  }
}

// ---------------------------------------------------------------------------
// column sums of t1/t2 (for C0 = exact mean of sims)
// ---------------------------------------------------------------------------
__global__ __launch_bounds__(256) void kcspart(const float* __restrict__ A,
                                               const float* __restrict__ B,
                                               float* __restrict__ pAB) {
  const int k = blockIdx.x * 256 + threadIdx.x;
  const int s = blockIdx.y;
  const float* src = blockIdx.z ? B : A;
  float acc = 0.f;
  for (int i = s * 128; i < s * 128 + 128; ++i) acc += src[(size_t)i * D_ + k];
  pAB[((size_t)blockIdx.z * 64 + s) * D_ + k] = acc;
}
__global__ __launch_bounds__(256) void kcsred(const float* __restrict__ pAB,
                                              float* __restrict__ csA,
                                              float* __restrict__ csB) {
  const int k = blockIdx.x * 256 + threadIdx.x;
  float a = 0.f, b = 0.f;
  for (int s = 0; s < 64; ++s) {
    a += pAB[(size_t)s * D_ + k];
    b += pAB[(size_t)(64 + s) * D_ + k];
  }
  csA[k] = a; csB[k] = b;
}
__global__ __launch_bounds__(256) void kc0(const float* __restrict__ csA,
                                           const float* __restrict__ csB,
                                           float* __restrict__ c0) {
  __shared__ float sb[4];
  float s = 0.f, d = 0.f;
  for (int k = threadIdx.x; k < D_; k += 256) s += csA[k] * csB[k];
  wave_reduce_add2(s, d);
  const int lane = threadIdx.x & 63, w = threadIdx.x >> 6;
  if (lane == 0) sb[w] = s;
  __syncthreads();
  if (threadIdx.x == 0)
    c0[0] = (sb[0] + sb[1] + sb[2] + sb[3]) / ((float)N_ * (float)N_);
}

// ---------------------------------------------------------------------------
// row/col stats of x
// ---------------------------------------------------------------------------
__global__ __launch_bounds__(256) void krowstats(const float* __restrict__ x,
                                                 float* __restrict__ mr) {
  __shared__ float sb[8];
  const int i = blockIdx.x;
  const float4* xr = reinterpret_cast<const float4*>(x + (size_t)i * M_);
  float s = 0.f, c = 0.f;
  for (int t = threadIdx.x; t < M_ / 4; t += 256) {
    float4 v = xr[t];
    s += v.x + v.y + v.z + v.w;
    c += (v.x > 0.f ? 1.f : 0.f) + (v.y > 0.f ? 1.f : 0.f) +
         (v.z > 0.f ? 1.f : 0.f) + (v.w > 0.f ? 1.f : 0.f);
  }
  wave_reduce_add2(s, c);
  const int lane = threadIdx.x & 63, w = threadIdx.x >> 6;
  if (lane == 0) { sb[w] = s; sb[4 + w] = c; }
  __syncthreads();
  if (threadIdx.x == 0) {
    s = sb[0] + sb[1] + sb[2] + sb[3];
    c = sb[4] + sb[5] + sb[6] + sb[7];
    mr[i] = s / (c + 1e-5f);
  }
}
__global__ __launch_bounds__(256) void kcolpart(const float* __restrict__ x,
                                                float* __restrict__ ps,
                                                float* __restrict__ pc) {
  const int j = blockIdx.x * 256 + threadIdx.x;
  const int slice = blockIdx.y;
  const int i0 = slice * (N_ / 64);
  float s = 0.f, c = 0.f;
  for (int i = i0; i < i0 + N_ / 64; ++i) {
    float v = x[(size_t)i * M_ + j];
    s += v;
    c += (v > 0.f ? 1.f : 0.f);
  }
  ps[(size_t)slice * M_ + j] = s;
  pc[(size_t)slice * M_ + j] = c;
}
__global__ __launch_bounds__(256) void kcolred(const float* __restrict__ ps,
                                               const float* __restrict__ pc,
                                               float* __restrict__ mc) {
  const int j = blockIdx.x * 256 + threadIdx.x;
  float s = 0.f, c = 0.f;
  for (int sl = 0; sl < 64; ++sl) {
    s += ps[(size_t)sl * M_ + j];
    c += pc[(size_t)sl * M_ + j];
  }
  mc[j] = s / (c + 1e-5f);
}
__global__ __launch_bounds__(256) void kmeans(const float* __restrict__ mr,
                                              const float* __restrict__ mc,
                                              float* __restrict__ scal) {
  __shared__ float sb[4];
  const float* src = blockIdx.x ? mc : mr;
  const int n = blockIdx.x ? M_ : N_;
  float s = 0.f, d = 0.f;
  for (int t = threadIdx.x; t < n; t += 256) s += src[t];
  wave_reduce_add2(s, d);
  const int lane = threadIdx.x & 63, w = threadIdx.x >> 6;
  if (lane == 0) sb[w] = s;
  __syncthreads();
  if (threadIdx.x == 0)
    scal[blockIdx.x] = (sb[0] + sb[1] + sb[2] + sb[3]) / (float)n;
}

// ---------------------------------------------------------------------------
// kgemm1: simb = bf16(A@B^T - C0), diag -> -C0.  A,B bf16 [8192][2048].
// 128x128 tile, BK=32, 256 thr / 4 waves (2x2), 16x16x32 MFMA.
// LDS granule layout [kgrp][row]: byte = kgrp*2048 + row*16 (conflict-free).
// ---------------------------------------------------------------------------
__global__ __launch_bounds__(256) void kgemm1(const u16* __restrict__ A,
                                              const u16* __restrict__ B,
                                              u16* __restrict__ C,
                                              const float* __restrict__ c0p) {
  __shared__ u16 As[4096];
  __shared__ u16 Bs[4096];
  const int tid = threadIdx.x, lane = tid & 63, w = tid >> 6;
  const int wm = w & 1, wn = w >> 1;
  const int row0 = blockIdx.y * 128, col0 = blockIdx.x * 128;
  const int fr = lane & 15, kg = lane >> 4;
  f4 acc[4][4] = {};

  for (int k0 = 0; k0 < D_; k0 += 32) {
#pragma unroll
    for (int c = 0; c < 2; ++c) {
      const int g = w * 128 + c * 64 + lane;      // granule index
      const int row = g & 127, kgrp = g >> 7;
      gload16(&A[(size_t)(row0 + row) * D_ + k0 + kgrp * 8],
              &As[(size_t)(w * 128 + c * 64) * 8]);
      gload16(&B[(size_t)(col0 + row) * D_ + k0 + kgrp * 8],
              &Bs[(size_t)(w * 128 + c * 64) * 8]);
    }
    __syncthreads();
    bf8 af[4], bb[4];
#pragma unroll
    for (int f = 0; f < 4; ++f) {
      af[f] = *(const bf8*)&As[kg * 1024 + (wm * 64 + f * 16 + fr) * 8];
      bb[f] = *(const bf8*)&Bs[kg * 1024 + (wn * 64 + f * 16 + fr) * 8];
    }
#pragma unroll
    for (int i = 0; i < 4; ++i)
#pragma unroll
      for (int j = 0; j < 4; ++j)
        acc[i][j] = mfma16(af[i], bb[j], acc[i][j]);
    __syncthreads();
  }

  const float c0 = c0p[0];
#pragma unroll
  for (int i = 0; i < 4; ++i)
#pragma unroll
    for (int j = 0; j < 4; ++j)
#pragma unroll
      for (int r = 0; r < 4; ++r) {
        const int gi = row0 + wm * 64 + i * 16 + kg * 4 + r;
        const int gj = col0 + wn * 64 + j * 16 + fr;
        float v = acc[i][j][r] - c0;
        if (gi == gj) v = -c0;
        C[(size_t)gi * N_ + gj] = f2b(v);
      }
}

// ---------------------------------------------------------------------------
// row max of shifted bf16 sims -> rmax (+C0 to unshift)
// ---------------------------------------------------------------------------
__global__ __launch_bounds__(256) void krowmaxb(const u16* __restrict__ sim,
                                                const float* __restrict__ c0p,
                                                float* __restrict__ rmax) {
  __shared__ float sb[4];
  const int i = blockIdx.x;
  const us8* row = (const us8*)(sim + (size_t)i * N_);
  float m = -1e30f;
  for (int t = threadIdx.x; t < N_ / 8; t += 256) {
    us8 v = row[t];
#pragma unroll
    for (int j = 0; j < 8; ++j) m = fmaxf(m, b2f(v[j]));
  }
#pragma unroll
  for (int o = 1; o < 64; o <<= 1) m = fmaxf(m, __shfl_xor(m, o, 64));
  const int lane = threadIdx.x & 63, w = threadIdx.x >> 6;
  if (lane == 0) sb[w] = m;
  __syncthreads();
  if (threadIdx.x == 0)
    rmax[i] = fmaxf(fmaxf(sb[0], sb[1]), fmaxf(sb[2], sb[3])) + c0p[0];
}

__global__ __launch_bounds__(256) void ktemp(const float* __restrict__ rmax,
                                             const float* __restrict__ gamma,
                                             const float* __restrict__ beta,
                                             float* __restrict__ rtemp) {
  const int j = blockIdx.x * 256 + threadIdx.x;
  if (j < N_) {
    float t = powf(rmax[j] + 0.001f, gamma[0]) * beta[0];
    rtemp[j] = 1.0f / t;
  }
}

// ---------------------------------------------------------------------------
// in-place bf16 softmax: logits L = (s_sh + C0) * rtemp[j], row softmax.
// ---------------------------------------------------------------------------
__global__ __launch_bounds__(256) void ksoftmaxb(u16* __restrict__ sim,
                                                 const float* __restrict__ rtemp,
                                                 const float* __restrict__ c0p) {
  __shared__ float srow[N_];  // 32 KB
  __shared__ float sb[8];
  const int i = blockIdx.x;
  u16* row = sim + (size_t)i * N_;
  const float c0 = c0p[0];
  const int lane = threadIdx.x & 63, w = threadIdx.x >> 6;

  float m = -1e30f;
  for (int t = threadIdx.x; t < N_ / 8; t += 256) {
    us8 v = ((const us8*)row)[t];
    float4 r0 = ((const float4*)rtemp)[t * 2 + 0];
    float4 r1 = ((const float4*)rtemp)[t * 2 + 1];
    float rt[8] = {r0.x, r0.y, r0.z, r0.w, r1.x, r1.y, r1.z, r1.w};
#pragma unroll
    for (int j = 0; j < 8; ++j) {
      float L = (b2f(v[j]) + c0) * rt[j];
      srow[t * 8 + j] = L;
      m = fmaxf(m, L);
    }
  }
#pragma unroll
  for (int o = 1; o < 64; o <<= 1) m = fmaxf(m, __shfl_xor(m, o, 64));
  if (lane == 0) sb[w] = m;
  __syncthreads();
  m = fmaxf(fmaxf(sb[0], sb[1]), fmaxf(sb[2], sb[3]));

  float s = 0.f;
  for (int t = threadIdx.x; t < N_; t += 256) {
    float e = __expf(srow[t] - m);
    srow[t] = e;
    s += e;
  }
  float d = 0.f;
  wave_reduce_add2(s, d);
  if (lane == 0) sb[4 + w] = s;
  __syncthreads();
  s = sb[4] + sb[5] + sb[6] + sb[7];
  const float inv = 1.0f / s;
  for (int t = threadIdx.x; t < N_ / 8; t += 256) {
    us8 o;
#pragma unroll
    for (int j = 0; j < 8; ++j) o[j] = f2b(srow[t * 8 + j] * inv);
    ((us8*)row)[t] = o;
  }
}

// ---------------------------------------------------------------------------
// kfused: 3-accumulator MFMA GEMM over K=8192:
//   s1=sim@x, s2=sim@mask, s3=sim@(mask*mr)  + epilogue.
// A = simb [8192][8192] bf16 (global_load_lds), B from xt [4096][8192] bf16
// (reg-staged; mask/mq derived in-register). BM=128,BN=64,BK=32, 4 waves 2x2.
// ---------------------------------------------------------------------------
__global__ __launch_bounds__(256) void kfused(const u16* __restrict__ sim,
                                              const u16* __restrict__ xt,
                                              const float* __restrict__ mr,
                                              const float* __restrict__ mc,
                                              const float* __restrict__ scal,
                                              const float* __restrict__ coef,
                                              float* __restrict__ out) {
  __shared__ u16 Asim[4096];                       // 128 rows x 32 k
  __shared__ u16 Bxs[2048], Bms[2048], Bqs[2048];  // 64 n x 32 k each
  const int tid = threadIdx.x, lane = tid & 63, w = tid >> 6;
  const int wm = w & 1, wn = w >> 1;
  const int row0 = blockIdx.y * 128, col0 = blockIdx.x * 64;
  const int fr = lane & 15, kg = lane >> 4;
  f4 a1[4][2] = {}, a2[4][2] = {}, a3[4][2] = {};

  for (int k0 = 0; k0 < N_; k0 += 32) {
    // A stage: async, granule layout [kgrp][row]
#pragma unroll
    for (int c = 0; c < 2; ++c) {
      const int g = w * 128 + c * 64 + lane;
      const int row = g & 127, kgrp = g >> 7;
      gload16(&sim[(size_t)(row0 + row) * N_ + k0 + kgrp * 8],
              &Asim[(size_t)(w * 128 + c * 64) * 8]);
    }
    // B stage: reg. wave w owns kgrp=w plane, lane = n.
    const int kb = k0 + w * 8;
    bf8 xv = *(const bf8*)&xt[(size_t)(col0 + lane) * N_ + kb];
    const float4 m0 = *(const float4*)&mr[kb];
    const float4 m1 = *(const float4*)&mr[kb + 4];
    const float mrv[8] = {m0.x, m0.y, m0.z, m0.w, m1.x, m1.y, m1.z, m1.w};
    bf8 mv, qv;
#pragma unroll
    for (int j = 0; j < 8; ++j) {
      const bool pos = ((u16)xv[j]) != 0;  // x>=0; bf16(x)>0 iff bits!=0
      mv[j] = pos ? (short)0x3F80 : (short)0;
      qv[j] = pos ? (short)f2b(mrv[j]) : (short)0;
    }
    *(bf8*)&Bxs[w * 512 + lane * 8] = xv;
    *(bf8*)&Bms[w * 512 + lane * 8] = mv;
    *(bf8*)&Bqs[w * 512 + lane * 8] = qv;
    __syncthreads();

    bf8 af[4], bx[2], bm[2], bq[2];
#pragma unroll
    for (int f = 0; f < 4; ++f)
      af[f] = *(const bf8*)&Asim[kg * 1024 + (wm * 64 + f * 16 + fr) * 8];
#pragma unroll
    for (int f = 0; f < 2; ++f) {
      const int n = wn * 32 + f * 16 + fr;
      bx[f] = *(const bf8*)&Bxs[kg * 512 + n * 8];
      bm[f] = *(const bf8*)&Bms[kg * 512 + n * 8];
      bq[f] = *(const bf8*)&Bqs[kg * 512 + n * 8];
    }
#pragma unroll
    for (int i = 0; i < 4; ++i)
#pragma unroll
      for (int j = 0; j < 2; ++j) {
        a1[i][j] = mfma16(af[i], bx[j], a1[i][j]);
        a2[i][j] = mfma16(af[i], bm[j], a2[i][j]);
        a3[i][j] = mfma16(af[i], bq[j], a3[i][j]);
      }
    __syncthreads();
  }

  const float c0 = coef[0], c1 = coef[1], c2 = coef[2];
  const float mrm = scal[0], mcm = scal[1];
#pragma unroll
  for (int j = 0; j < 2; ++j) {
    const int gj = col0 + wn * 32 + j * 16 + fr;
    const float mcc = c1 * (mc[gj] - mcm);
#pragma unroll
    for (int i = 0; i < 4; ++i)
#pragma unroll
      for (int r = 0; r < 4; ++r) {
        const int gi = row0 + wm * 64 + i * 16 + kg * 4 + r;
        const float mri = mr[gi];
        const float sc = a2[i][j][r] + 1e-4f;
        const float inv = 1.0f / sc;
        const float o = a1[i][j][r] * inv + c0 * (mri - a3[i][j][r] * inv) +
                        mcc + c2 * (mri - mrm);
        out[(size_t)gi * M_ + gj] = o;
      }
  }
}

// ---------------------------------------------------------------------------
// launch
// ---------------------------------------------------------------------------
extern "C" void kernel_launch(void* const* d_in, const int* in_sizes, int n_in,
                              void* d_out, int out_size, void* d_ws,
                              size_t ws_size, hipStream_t stream) {
  const float* t1 = (const float*)d_in[0];
  const float* t2 = (const float*)d_in[1];
  const float* x = (const float*)d_in[2];
  const float* beta = (const float*)d_in[3];
  const float* gamma = (const float*)d_in[4];
  const float* coef = (const float*)d_in[5];
  float* out = (float*)d_out;

  // ws layout (bytes):
  //   simb [8192*8192] bf16 @ 0            = 134217728
  //   t1b  [8192*2048] bf16 @ 134217728    = 33554432
  //   t2b  [8192*2048] bf16 @ 167772160    = 33554432
  //   xbT  [4096*8192] bf16 @ 201326592    = 67108864
  //   aux floats @ 268435456 (~2.3 MB)     -> total ~270.7 MB
  char* wsb = (char*)d_ws;
  u16* simb = (u16*)wsb;
  u16* t1b = (u16*)(wsb + 134217728);
  u16* t2b = (u16*)(wsb + 167772160);
  u16* xbT = (u16*)(wsb + 201326592);
  float* aux = (float*)(wsb + 268435456);
  float* mr = aux + 0;          // 8192
  float* mc = aux + 8192;       // 4096
  float* rmax = aux + 16384;    // 8192
  float* rtemp = aux + 24576;   // 8192
  float* scal = aux + 32768;    // 2
  float* c0 = aux + 32772;      // 1
  float* csA = aux + 40960;     // 2048
  float* csB = aux + 43008;     // 2048
  float* cps = aux + 45056;     // 262144
  float* cpc = aux + 307200;    // 262144
  float* pAB = cps;             // lifetime: before kcolpart

  // conversions
  kcvt<<<2048, 256, 0, stream>>>(t1, t1b, N_ * D_ / 8);
  kcvt<<<2048, 256, 0, stream>>>(t2, t2b, N_ * D_ / 8);
  kcvtxt<<<dim3(M_ / 64, N_ / 64), 256, 0, stream>>>(x, xbT);

  // C0 = exact mean of sims
  kcspart<<<dim3(D_ / 256, 64, 2), 256, 0, stream>>>(t1, t2, pAB);
  kcsred<<<D_ / 256, 256, 0, stream>>>(pAB, csA, csB);
  kc0<<<1, 256, 0, stream>>>(csA, csB, c0);

  // x stats
  krowstats<<<N_, 256, 0, stream>>>(x, mr);
  kcolpart<<<dim3(M_ / 256, 64), 256, 0, stream>>>(x, cps, cpc);
  kcolred<<<M_ / 256, 256, 0, stream>>>(cps, cpc, mc);
  kmeans<<<2, 256, 0, stream>>>(mr, mc, scal);

  // sims (shifted bf16) + softmax
  kgemm1<<<dim3(N_ / 128, N_ / 128), 256, 0, stream>>>(t1b, t2b, simb, c0);
  krowmaxb<<<N_, 256, 0, stream>>>(simb, c0, rmax);
  ktemp<<<N_ / 256, 256, 0, stream>>>(rmax, gamma, beta, rtemp);
  ksoftmaxb<<<N_, 256, 0, stream>>>(simb, rtemp, c0);

  // fused triple GEMM + epilogue
  kfused<<<dim3(M_ / 64, N_ / 128), 256, 0, stream>>>(simb, xbT, mr, mc, scal,
                                                      coef, out);
}

// Round 5
// 3075.687 us; speedup vs baseline: 6.6740x; 1.4002x over previous
//
#include <hip/hip_runtime.h>
#include <cstddef>
#include <cstdint>

constexpr int N_ = 8192;   // rows of x / sims
constexpr int D_ = 2048;   // onehot feature dim
constexpr int M_ = 4096;   // item dim

typedef unsigned short u16;
typedef __attribute__((ext_vector_type(8))) unsigned short us8;
typedef __attribute__((ext_vector_type(8))) short bf8;     // 8 x bf16 (4 VGPR)
typedef __attribute__((ext_vector_type(4))) float f4;

// ---------------------------------------------------------------------------
// helpers
// ---------------------------------------------------------------------------
__device__ __forceinline__ u16 f2b(float f) {   // fp32 -> bf16 RNE
  union { float f; unsigned u; } v{f};
  unsigned r = v.u + 0x7fffu + ((v.u >> 16) & 1u);
  return (u16)(r >> 16);
}
__device__ __forceinline__ float b2f(u16 h) {
  union { unsigned u; float f; } v{(unsigned)h << 16};
  return v.f;
}
__device__ __forceinline__ void wave_reduce_add2(float& a, float& b) {
#pragma unroll
  for (int o = 1; o < 64; o <<= 1) {
    a += __shfl_xor(a, o, 64);
    b += __shfl_xor(b, o, 64);
  }
}
// async global->LDS, 16B per lane. lds base must be wave-uniform.
__device__ __forceinline__ void gload16(const void* g, void* lds) {
  __builtin_amdgcn_global_load_lds(
      (const __attribute__((address_space(1))) unsigned int*)g,
      (__attribute__((address_space(3))) unsigned int*)lds, 16, 0, 0);
}
__device__ __forceinline__ f4 mfma16(bf8 a, bf8 b, f4 c) {
  return __builtin_amdgcn_mfma_f32_16x16x32_bf16(a, b, c, 0, 0, 0);
}

// ---------------------------------------------------------------------------
// fp32 -> bf16 convert (grid-stride, 8 elems/thread/iter)
// ---------------------------------------------------------------------------
__global__ __launch_bounds__(256) void kcvt(const float* __restrict__ s,
                                            u16* __restrict__ d, int n8) {
  for (int i = blockIdx.x * 256 + threadIdx.x; i < n8; i += gridDim.x * 256) {
    float4 a = ((const float4*)s)[i * 2 + 0];
    float4 b = ((const float4*)s)[i * 2 + 1];
    us8 v;
    v[0] = f2b(a.x); v[1] = f2b(a.y); v[2] = f2b(a.z); v[3] = f2b(a.w);
    v[4] = f2b(b.x); v[5] = f2b(b.y); v[6] = f2b(b.z); v[7] = f2b(b.w);
    ((us8*)d)[i] = v;
  }
}

// ---------------------------------------------------------------------------
// kprepB: B1T[j][k] = bf16(x[k][j] - c0*mr[k]*(x>0)),  maskT[j][k] = bf16(x>0)
// transpose via LDS, 64x64 tiles.
// ---------------------------------------------------------------------------
__global__ __launch_bounds__(256) void kprepB(const float* __restrict__ x,
                                              const float* __restrict__ mr,
                                              const float* __restrict__ coef,
                                              u16* __restrict__ b1t,
                                              u16* __restrict__ mkt) {
  __shared__ u16 s1[64][72];
  __shared__ u16 s2[64][72];
  const int k0 = blockIdx.y * 64;  // x row block (k)
  const int n0 = blockIdx.x * 64;  // x col block (n)
  const int t = threadIdx.x;
  const float c0 = coef[0];
#pragma unroll
  for (int p = 0; p < 4; ++p) {
    const int r = (t >> 4) + 16 * p, c = (t & 15) * 4;
    float4 v = *(const float4*)&x[(size_t)(k0 + r) * M_ + n0 + c];
    const float s = c0 * mr[k0 + r];
    const bool p0 = v.x > 0.f, p1 = v.y > 0.f, p2 = v.z > 0.f, p3 = v.w > 0.f;
    s1[r][c + 0] = f2b(p0 ? v.x - s : v.x);
    s1[r][c + 1] = f2b(p1 ? v.y - s : v.y);
    s1[r][c + 2] = f2b(p2 ? v.z - s : v.z);
    s1[r][c + 3] = f2b(p3 ? v.w - s : v.w);
    s2[r][c + 0] = p0 ? 0x3F80 : 0; s2[r][c + 1] = p1 ? 0x3F80 : 0;
    s2[r][c + 2] = p2 ? 0x3F80 : 0; s2[r][c + 3] = p3 ? 0x3F80 : 0;
  }
  __syncthreads();
#pragma unroll
  for (int q = 0; q < 2; ++q) {
    const int o = (q * 256 + t) * 8;
    const int nl = o >> 6, kc = o & 63;
    us8 v1, v2;
#pragma unroll
    for (int j = 0; j < 8; ++j) { v1[j] = s1[kc + j][nl]; v2[j] = s2[kc + j][nl]; }
    *(us8*)&b1t[(size_t)(n0 + nl) * N_ + k0 + kc] = v1;
    *(us8*)&mkt[(size_t)(n0 + nl) * N_ + k0 + kc] = v2;
  }
}

// ---------------------------------------------------------------------------
// column sums of t1/t2 (for C0 = exact mean of sims)
// ---------------------------------------------------------------------------
__global__ __launch_bounds__(256) void kcspart(const float* __restrict__ A,
                                               const float* __restrict__ B,
                                               float* __restrict__ pAB) {
  const int k = blockIdx.x * 256 + threadIdx.x;
  const int s = blockIdx.y;
  const float* src = blockIdx.z ? B : A;
  float acc = 0.f;
  for (int i = s * 128; i < s * 128 + 128; ++i) acc += src[(size_t)i * D_ + k];
  pAB[((size_t)blockIdx.z * 64 + s) * D_ + k] = acc;
}
__global__ __launch_bounds__(256) void kcsred(const float* __restrict__ pAB,
                                              float* __restrict__ csA,
                                              float* __restrict__ csB) {
  const int k = blockIdx.x * 256 + threadIdx.x;
  float a = 0.f, b = 0.f;
  for (int s = 0; s < 64; ++s) {
    a += pAB[(size_t)s * D_ + k];
    b += pAB[(size_t)(64 + s) * D_ + k];
  }
  csA[k] = a; csB[k] = b;
}
__global__ __launch_bounds__(256) void kc0(const float* __restrict__ csA,
                                           const float* __restrict__ csB,
                                           float* __restrict__ c0) {
  __shared__ float sb[4];
  float s = 0.f, d = 0.f;
  for (int k = threadIdx.x; k < D_; k += 256) s += csA[k] * csB[k];
  wave_reduce_add2(s, d);
  const int lane = threadIdx.x & 63, w = threadIdx.x >> 6;
  if (lane == 0) sb[w] = s;
  __syncthreads();
  if (threadIdx.x == 0)
    c0[0] = (sb[0] + sb[1] + sb[2] + sb[3]) / ((float)N_ * (float)N_);
}

// ---------------------------------------------------------------------------
// row/col stats of x
// ---------------------------------------------------------------------------
__global__ __launch_bounds__(256) void krowstats(const float* __restrict__ x,
                                                 float* __restrict__ mr) {
  __shared__ float sb[8];
  const int i = blockIdx.x;
  const float4* xr = reinterpret_cast<const float4*>(x + (size_t)i * M_);
  float s = 0.f, c = 0.f;
  for (int t = threadIdx.x; t < M_ / 4; t += 256) {
    float4 v = xr[t];
    s += v.x + v.y + v.z + v.w;
    c += (v.x > 0.f ? 1.f : 0.f) + (v.y > 0.f ? 1.f : 0.f) +
         (v.z > 0.f ? 1.f : 0.f) + (v.w > 0.f ? 1.f : 0.f);
  }
  wave_reduce_add2(s, c);
  const int lane = threadIdx.x & 63, w = threadIdx.x >> 6;
  if (lane == 0) { sb[w] = s; sb[4 + w] = c; }
  __syncthreads();
  if (threadIdx.x == 0) {
    s = sb[0] + sb[1] + sb[2] + sb[3];
    c = sb[4] + sb[5] + sb[6] + sb[7];
    mr[i] = s / (c + 1e-5f);
  }
}
__global__ __launch_bounds__(256) void kcolpart(const float* __restrict__ x,
                                                float* __restrict__ ps,
                                                float* __restrict__ pc) {
  const int j = blockIdx.x * 256 + threadIdx.x;
  const int slice = blockIdx.y;
  const int i0 = slice * (N_ / 64);
  float s = 0.f, c = 0.f;
  for (int i = i0; i < i0 + N_ / 64; ++i) {
    float v = x[(size_t)i * M_ + j];
    s += v;
    c += (v > 0.f ? 1.f : 0.f);
  }
  ps[(size_t)slice * M_ + j] = s;
  pc[(size_t)slice * M_ + j] = c;
}
__global__ __launch_bounds__(256) void kcolred(const float* __restrict__ ps,
                                               const float* __restrict__ pc,
                                               float* __restrict__ mc) {
  const int j = blockIdx.x * 256 + threadIdx.x;
  float s = 0.f, c = 0.f;
  for (int sl = 0; sl < 64; ++sl) {
    s += ps[(size_t)sl * M_ + j];
    c += pc[(size_t)sl * M_ + j];
  }
  mc[j] = s / (c + 1e-5f);
}
__global__ __launch_bounds__(256) void kmeans(const float* __restrict__ mr,
                                              const float* __restrict__ mc,
                                              float* __restrict__ scal) {
  __shared__ float sb[4];
  const float* src = blockIdx.x ? mc : mr;
  const int n = blockIdx.x ? M_ : N_;
  float s = 0.f, d = 0.f;
  for (int t = threadIdx.x; t < n; t += 256) s += src[t];
  wave_reduce_add2(s, d);
  const int lane = threadIdx.x & 63, w = threadIdx.x >> 6;
  if (lane == 0) sb[w] = s;
  __syncthreads();
  if (threadIdx.x == 0)
    scal[blockIdx.x] = (sb[0] + sb[1] + sb[2] + sb[3]) / (float)n;
}

// ---------------------------------------------------------------------------
// kgemm1: simb = bf16(A@B^T - C0), diag -> -C0.  A,B bf16 [8192][2048].
// 128x128 tile, BK=32, 256 thr / 4 waves (2x2), 16x16x32 MFMA. (validated r3)
// ---------------------------------------------------------------------------
__global__ __launch_bounds__(256) void kgemm1(const u16* __restrict__ A,
                                              const u16* __restrict__ B,
                                              u16* __restrict__ C,
                                              const float* __restrict__ c0p) {
  __shared__ u16 As[4096];
  __shared__ u16 Bs[4096];
  const int tid = threadIdx.x, lane = tid & 63, w = tid >> 6;
  const int wm = w & 1, wn = w >> 1;
  const int row0 = blockIdx.y * 128, col0 = blockIdx.x * 128;
  const int fr = lane & 15, kg = lane >> 4;
  f4 acc[4][4] = {};

  for (int k0 = 0; k0 < D_; k0 += 32) {
#pragma unroll
    for (int c = 0; c < 2; ++c) {
      gload16(&A[(size_t)(row0 + c * 64 + lane) * D_ + k0 + w * 8],
              &As[w * 1024 + c * 512]);
      gload16(&B[(size_t)(col0 + c * 64 + lane) * D_ + k0 + w * 8],
              &Bs[w * 1024 + c * 512]);
    }
    __syncthreads();
    bf8 af[4], bb[4];
#pragma unroll
    for (int f = 0; f < 4; ++f) {
      af[f] = *(const bf8*)&As[kg * 1024 + (wm * 64 + f * 16 + fr) * 8];
      bb[f] = *(const bf8*)&Bs[kg * 1024 + (wn * 64 + f * 16 + fr) * 8];
    }
#pragma unroll
    for (int i = 0; i < 4; ++i)
#pragma unroll
      for (int j = 0; j < 4; ++j)
        acc[i][j] = mfma16(af[i], bb[j], acc[i][j]);
    __syncthreads();
  }

  const float c0 = c0p[0];
#pragma unroll
  for (int i = 0; i < 4; ++i)
#pragma unroll
    for (int j = 0; j < 4; ++j)
#pragma unroll
      for (int r = 0; r < 4; ++r) {
        const int gi = row0 + wm * 64 + i * 16 + kg * 4 + r;
        const int gj = col0 + wn * 64 + j * 16 + fr;
        float v = acc[i][j][r] - c0;
        if (gi == gj) v = -c0;
        C[(size_t)gi * N_ + gj] = f2b(v);
      }
}

// ---------------------------------------------------------------------------
// row max of shifted bf16 sims -> rmax (+C0 to unshift)
// ---------------------------------------------------------------------------
__global__ __launch_bounds__(256) void krowmaxb(const u16* __restrict__ sim,
                                                const float* __restrict__ c0p,
                                                float* __restrict__ rmax) {
  __shared__ float sb[4];
  const int i = blockIdx.x;
  const us8* row = (const us8*)(sim + (size_t)i * N_);
  float m = -1e30f;
  for (int t = threadIdx.x; t < N_ / 8; t += 256) {
    us8 v = row[t];
#pragma unroll
    for (int j = 0; j < 8; ++j) m = fmaxf(m, b2f(v[j]));
  }
#pragma unroll
  for (int o = 1; o < 64; o <<= 1) m = fmaxf(m, __shfl_xor(m, o, 64));
  const int lane = threadIdx.x & 63, w = threadIdx.x >> 6;
  if (lane == 0) sb[w] = m;
  __syncthreads();
  if (threadIdx.x == 0)
    rmax[i] = fmaxf(fmaxf(sb[0], sb[1]), fmaxf(sb[2], sb[3])) + c0p[0];
}

__global__ __launch_bounds__(256) void ktemp(const float* __restrict__ rmax,
                                             const float* __restrict__ gamma,
                                             const float* __restrict__ beta,
                                             float* __restrict__ rtemp) {
  const int j = blockIdx.x * 256 + threadIdx.x;
  if (j < N_) {
    float t = powf(rmax[j] + 0.001f, gamma[0]) * beta[0];
    rtemp[j] = 1.0f / t;
  }
}

// ---------------------------------------------------------------------------
// in-place bf16 softmax: logits L = (s_sh + C0) * rtemp[j], row softmax.
// ---------------------------------------------------------------------------
__global__ __launch_bounds__(256) void ksoftmaxb(u16* __restrict__ sim,
                                                 const float* __restrict__ rtemp,
                                                 const float* __restrict__ c0p) {
  __shared__ float srow[N_];  // 32 KB
  __shared__ float sb[8];
  const int i = blockIdx.x;
  u16* row = sim + (size_t)i * N_;
  const float c0 = c0p[0];
  const int lane = threadIdx.x & 63, w = threadIdx.x >> 6;

  float m = -1e30f;
  for (int t = threadIdx.x; t < N_ / 8; t += 256) {
    us8 v = ((const us8*)row)[t];
    float4 r0 = ((const float4*)rtemp)[t * 2 + 0];
    float4 r1 = ((const float4*)rtemp)[t * 2 + 1];
    float rt[8] = {r0.x, r0.y, r0.z, r0.w, r1.x, r1.y, r1.z, r1.w};
#pragma unroll
    for (int j = 0; j < 8; ++j) {
      float L = (b2f(v[j]) + c0) * rt[j];
      srow[t * 8 + j] = L;
      m = fmaxf(m, L);
    }
  }
#pragma unroll
  for (int o = 1; o < 64; o <<= 1) m = fmaxf(m, __shfl_xor(m, o, 64));
  if (lane == 0) sb[w] = m;
  __syncthreads();
  m = fmaxf(fmaxf(sb[0], sb[1]), fmaxf(sb[2], sb[3]));

  float s = 0.f;
  for (int t = threadIdx.x; t < N_; t += 256) {
    float e = __expf(srow[t] - m);
    srow[t] = e;
    s += e;
  }
  float d = 0.f;
  wave_reduce_add2(s, d);
  if (lane == 0) sb[4 + w] = s;
  __syncthreads();
  s = sb[4] + sb[5] + sb[6] + sb[7];
  const float inv = 1.0f / s;
  for (int t = threadIdx.x; t < N_ / 8; t += 256) {
    us8 o;
#pragma unroll
    for (int j = 0; j < 8; ++j) o[j] = f2b(srow[t * 8 + j] * inv);
    ((us8*)row)[t] = o;
  }
}

// ---------------------------------------------------------------------------
// kfused: DOUBLE MFMA GEMM over K=8192 (folded):
//   s1c = sim @ B1   (B1 = x - c0*mask*mr)
//   s2  = sim @ mask
//   out = s1c/(s2+1e-4) + c0*mr_i + c1*(mc_j - mcm) + c2*(mr_i - mrm)
// All operands staged via global_load_lds. BM=128,BN=64,BK=32, 4 waves 2x2.
// XCD-swizzled block mapping (4096 blocks, bijective).
// ---------------------------------------------------------------------------
__global__ __launch_bounds__(256) void kfused(const u16* __restrict__ sim,
                                              const u16* __restrict__ b1t,
                                              const u16* __restrict__ mkt,
                                              const float* __restrict__ mr,
                                              const float* __restrict__ mc,
                                              const float* __restrict__ scal,
                                              const float* __restrict__ coef,
                                              float* __restrict__ out) {
  __shared__ u16 As[4096];              // 128 rows x 32 k, [kgrp][row] granules
  __shared__ u16 B1s[2048], B2s[2048];  // 64 n x 32 k, [kgrp][n] granules
  const int tid = threadIdx.x, lane = tid & 63, w = tid >> 6;
  const int wm = w & 1, wn = w >> 1;
  // bijective XCD swizzle: 4096 blocks, 8 XCDs, 512 per XCD.
  const int lid = blockIdx.y * gridDim.x + blockIdx.x;
  const int swz = (lid & 7) * 512 + (lid >> 3);
  const int row0 = (swz >> 6) * 128, col0 = (swz & 63) * 64;
  const int fr = lane & 15, kg = lane >> 4;
  f4 a1[4][2] = {}, a2[4][2] = {};

  for (int k0 = 0; k0 < N_; k0 += 32) {
#pragma unroll
    for (int c = 0; c < 2; ++c)
      gload16(&sim[(size_t)(row0 + c * 64 + lane) * N_ + k0 + w * 8],
              &As[w * 1024 + c * 512]);
    gload16(&b1t[(size_t)(col0 + lane) * N_ + k0 + w * 8], &B1s[w * 512]);
    gload16(&mkt[(size_t)(col0 + lane) * N_ + k0 + w * 8], &B2s[w * 512]);
    __syncthreads();

    bf8 af[4], b1[2], b2[2];
#pragma unroll
    for (int f = 0; f < 4; ++f)
      af[f] = *(const bf8*)&As[kg * 1024 + (wm * 64 + f * 16 + fr) * 8];
#pragma unroll
    for (int f = 0; f < 2; ++f) {
      const int n = wn * 32 + f * 16 + fr;
      b1[f] = *(const bf8*)&B1s[kg * 512 + n * 8];
      b2[f] = *(const bf8*)&B2s[kg * 512 + n * 8];
    }
#pragma unroll
    for (int i = 0; i < 4; ++i)
#pragma unroll
      for (int j = 0; j < 2; ++j) {
        a1[i][j] = mfma16(af[i], b1[j], a1[i][j]);
        a2[i][j] = mfma16(af[i], b2[j], a2[i][j]);
      }
    __syncthreads();
  }

  const float c0 = coef[0], c1 = coef[1], c2 = coef[2];
  const float mrm = scal[0], mcm = scal[1];
#pragma unroll
  for (int j = 0; j < 2; ++j) {
    const int gj = col0 + wn * 32 + j * 16 + fr;
    const float mcc = c1 * (mc[gj] - mcm);
#pragma unroll
    for (int i = 0; i < 4; ++i)
#pragma unroll
      for (int r = 0; r < 4; ++r) {
        const int gi = row0 + wm * 64 + i * 16 + kg * 4 + r;
        const float mri = mr[gi];
        const float inv = 1.0f / (a2[i][j][r] + 1e-4f);
        const float o = a1[i][j][r] * inv + c0 * mri + mcc + c2 * (mri - mrm);
        out[(size_t)gi * M_ + gj] = o;
      }
  }
}

// ---------------------------------------------------------------------------
// launch
// ---------------------------------------------------------------------------
extern "C" void kernel_launch(void* const* d_in, const int* in_sizes, int n_in,
                              void* d_out, int out_size, void* d_ws,
                              size_t ws_size, hipStream_t stream) {
  const float* t1 = (const float*)d_in[0];
  const float* t2 = (const float*)d_in[1];
  const float* x = (const float*)d_in[2];
  const float* beta = (const float*)d_in[3];
  const float* gamma = (const float*)d_in[4];
  const float* coef = (const float*)d_in[5];
  float* out = (float*)d_out;

  // ws layout (bytes):
  //   simb  [8192*8192] bf16 @ 0           = 134217728
  //   t1b/t2b @ 134217728 (33554432 each)  -- dead after kgemm1
  //   maskT [4096*8192] bf16 @ 134217728   -- overlays t1b+t2b (after kgemm1)
  //   B1T   [4096*8192] bf16 @ 201326592   = 67108864
  //   aux floats @ 268435456 (~2.3 MB)     -> total ~270.7 MB (same as r3)
  char* wsb = (char*)d_ws;
  u16* simb = (u16*)wsb;
  u16* t1b = (u16*)(wsb + 134217728);
  u16* t2b = (u16*)(wsb + 167772160);
  u16* maskT = (u16*)(wsb + 134217728);  // overlays t1b/t2b, written by kprepB
  u16* b1T = (u16*)(wsb + 201326592);
  float* aux = (float*)(wsb + 268435456);
  float* mr = aux + 0;          // 8192
  float* mc = aux + 8192;       // 4096
  float* rmax = aux + 16384;    // 8192
  float* rtemp = aux + 24576;   // 8192
  float* scal = aux + 32768;    // 2
  float* c0 = aux + 32772;      // 1
  float* csA = aux + 40960;     // 2048
  float* csB = aux + 43008;     // 2048
  float* cps = aux + 45056;     // 262144
  float* cpc = aux + 307200;    // 262144
  float* pAB = cps;             // lifetime: before kcolpart

  // conversions of t1/t2
  kcvt<<<2048, 256, 0, stream>>>(t1, t1b, N_ * D_ / 8);
  kcvt<<<2048, 256, 0, stream>>>(t2, t2b, N_ * D_ / 8);

  // C0 = exact mean of sims
  kcspart<<<dim3(D_ / 256, 64, 2), 256, 0, stream>>>(t1, t2, pAB);
  kcsred<<<D_ / 256, 256, 0, stream>>>(pAB, csA, csB);
  kc0<<<1, 256, 0, stream>>>(csA, csB, c0);

  // x stats
  krowstats<<<N_, 256, 0, stream>>>(x, mr);
  kcolpart<<<dim3(M_ / 256, 64), 256, 0, stream>>>(x, cps, cpc);
  kcolred<<<M_ / 256, 256, 0, stream>>>(cps, cpc, mc);
  kmeans<<<2, 256, 0, stream>>>(mr, mc, scal);

  // sims (shifted bf16)
  kgemm1<<<dim3(N_ / 128, N_ / 128), 256, 0, stream>>>(t1b, t2b, simb, c0);

  // B1/mask prep (after kgemm1: maskT overlays t1b/t2b)
  kprepB<<<dim3(M_ / 64, N_ / 64), 256, 0, stream>>>(x, mr, coef, b1T, maskT);

  // softmax chain
  krowmaxb<<<N_, 256, 0, stream>>>(simb, c0, rmax);
  ktemp<<<N_ / 256, 256, 0, stream>>>(rmax, gamma, beta, rtemp);
  ksoftmaxb<<<N_, 256, 0, stream>>>(simb, rtemp, c0);

  // fused double GEMM + epilogue
  kfused<<<dim3(M_ / 64, N_ / 128), 256, 0, stream>>>(simb, b1T, maskT, mr, mc,
                                                      scal, coef, out);
}